// Round 8
// baseline (4998.949 us; speedup 1.0000x reference)
//
#include <hip/hip_runtime.h>
#include <math.h>

#define EDIM 512
#define HDIM 1024
#define VDIM 32000
#define BDIM 128
#define SDIM 64
#define NG 4096

typedef __bf16 bf16;
typedef bf16 bf16x8 __attribute__((ext_vector_type(8)));
typedef float f32x4 __attribute__((ext_vector_type(4)));

// async global->LDS, 16B per lane. LDS dest linear in tid (wave-uniform base +
// lane*16) for all staging layouts here.
__device__ __forceinline__ void gload16(const bf16* g, bf16* l) {
    __builtin_amdgcn_global_load_lds(
        (const __attribute__((address_space(1))) void*)g,
        (__attribute__((address_space(3))) void*)l, 16, 0, 0);
}

// counted waitcnt + raw barrier helpers (T4: never drain vmcnt to 0 in-loop)
#define VMCNT(N)                                              \
    {                                                         \
        asm volatile("s_waitcnt vmcnt(" #N ")" ::: "memory"); \
        __builtin_amdgcn_sched_barrier(0);                    \
    }
#define BAR() __builtin_amdgcn_s_barrier()

// meta int layout: [0]=T,[1]=total,[2]=bs_last,[3]=pad,[4..67]=bsz,[68..131]=off,
// [132..132+8192)=src_row
#define META_INTS (132 + BDIM * SDIM)

__global__ void meta_kernel(const int* __restrict__ lengths, int* __restrict__ meta) {
    __shared__ int s_bsz[SDIM];
    __shared__ int s_off[SDIM];
    int t = threadIdx.x;  // 64 threads
    int cnt = 0;
    for (int b = 0; b < BDIM; ++b) cnt += (lengths[b] > t) ? 1 : 0;
    s_bsz[t] = cnt;
    __syncthreads();
    if (t == 0) {
        int acc = 0;
        for (int i = 0; i < SDIM; ++i) { s_off[i] = acc; acc += s_bsz[i]; }
        int T = lengths[0];
        meta[0] = T;
        meta[1] = acc;
        meta[2] = s_bsz[T - 1];
        meta[3] = 0;
    }
    __syncthreads();
    meta[4 + t] = s_bsz[t];
    meta[68 + t] = s_off[t];
    for (int b = 0; b < s_bsz[t]; ++b) meta[132 + s_off[t] + b] = t * BDIM + b;
}

// fp32 -> bf16 (RNE), 8 elems/thread
__global__ void cvt_bf16_kernel(const float* __restrict__ src, bf16* __restrict__ dst, int n8) {
    int idx = blockIdx.x * 256 + threadIdx.x;
    if (idx >= n8) return;
    float4 a = ((const float4*)src)[(size_t)idx * 2];
    float4 b = ((const float4*)src)[(size_t)idx * 2 + 1];
    float v[8] = {a.x, a.y, a.z, a.w, b.x, b.y, b.z, b.w};
    bf16x8 o;
#pragma unroll
    for (int i = 0; i < 8; ++i) o[i] = (bf16)v[i];
    *(bf16x8*)(dst + (size_t)idx * 8) = o;
}

// build x0 rows (r = t*B + b) as bf16 hi/lo split
__global__ void gather_x0_kernel(const float* __restrict__ features,
                                 const int* __restrict__ tokens,
                                 const float* __restrict__ embedW,
                                 bf16* __restrict__ xhi, bf16* __restrict__ xlo) {
    int idx = blockIdx.x * 256 + threadIdx.x;  // 8192 * 64
    int r = idx >> 6;
    int c = (idx & 63) * 8;
    int t = r >> 7, b = r & 127;
    const float* src = (t == 0) ? (features + (size_t)b * EDIM)
                                : (embedW + (size_t)tokens[b * SDIM + (t - 1)] * EDIM);
    float4 a = *(const float4*)(src + c);
    float4 d = *(const float4*)(src + c + 4);
    float v[8] = {a.x, a.y, a.z, a.w, d.x, d.y, d.z, d.w};
    bf16x8 hi, lo;
#pragma unroll
    for (int i = 0; i < 8; ++i) {
        hi[i] = (bf16)v[i];
        lo[i] = (bf16)(v[i] - (float)hi[i]);
    }
    size_t o = (size_t)r * EDIM + c;
    *(bf16x8*)(xhi + o) = hi;
    *(bf16x8*)(xlo + o) = lo;
}

// C[M x N] = (Ahi + Alo) @ B^T + bias0 + bias1
// Tile 128x128, BK=32, 256 threads = 4 waves (2x2), each wave 64x64.
// Staging: global_load_lds 16B/lane, double-buffered, counted-vmcnt pipeline:
// loads for tile i+1 stay in flight while tile i computes (never drain to 0).
__global__ __launch_bounds__(256) void gemm_bulk(
    const bf16* __restrict__ Ahi, const bf16* __restrict__ Alo,
    const bf16* __restrict__ Bb, float* __restrict__ C,
    const float* __restrict__ bias0, const float* __restrict__ bias1,
    const int* __restrict__ srcrow, const int* __restrict__ mdyn,
    int M, int K, int ldc, int permute, int ntc) {
    const int Mr = mdyn ? mdyn[0] : M;
    const int bm = blockIdx.x;
    const int bn = blockIdx.y;
    if (bm * 128 >= Mr) return;

    const int tid = threadIdx.x;
    const int wave = tid >> 6, lane = tid & 63;
    const int kg = lane >> 4, rl = lane & 15;
    const int wm = wave >> 1, wn = wave & 1;

    __shared__ bf16 sAhi[2][4][128][8];
    __shared__ bf16 sAlo[2][4][128][8];
    __shared__ bf16 sB[2][4][128][8];

    const int sr = tid & 127;
    const int skg = tid >> 7;
    int arow_g = bm * 128 + sr;
    int arow = (arow_g < Mr) ? (srcrow ? srcrow[arow_g] : arow_g) : (srcrow ? srcrow[0] : 0);
    const bf16* pAhi = Ahi + (size_t)arow * K + skg * 8;
    const bf16* pAlo = Alo + (size_t)arow * K + skg * 8;
    const bf16* pB = Bb + ((size_t)bn * 128 + sr) * K + skg * 8;

    f32x4 acc[4][4] = {};

#define STAGE(BUF, KT)                                        \
    {                                                         \
        gload16(pAhi + (KT), &sAhi[BUF][skg][sr][0]);         \
        gload16(pAhi + (KT) + 16, &sAhi[BUF][skg + 2][sr][0]);\
        gload16(pAlo + (KT), &sAlo[BUF][skg][sr][0]);         \
        gload16(pAlo + (KT) + 16, &sAlo[BUF][skg + 2][sr][0]);\
        gload16(pB + (KT), &sB[BUF][skg][sr][0]);             \
        gload16(pB + (KT) + 16, &sB[BUF][skg + 2][sr][0]);    \
    }

    auto mfma_step = [&](int buf) {
        bf16x8 bfr[4];
#pragma unroll
        for (int nt = 0; nt < 4; ++nt)
            bfr[nt] = *(const bf16x8*)&sB[buf][kg][wn * 64 + nt * 16 + rl][0];
#pragma unroll
        for (int mt = 0; mt < 4; ++mt) {
            bf16x8 ah = *(const bf16x8*)&sAhi[buf][kg][wm * 64 + mt * 16 + rl][0];
            bf16x8 al = *(const bf16x8*)&sAlo[buf][kg][wm * 64 + mt * 16 + rl][0];
#pragma unroll
            for (int nt = 0; nt < 4; ++nt) {
                acc[mt][nt] = __builtin_amdgcn_mfma_f32_16x16x32_bf16(ah, bfr[nt], acc[mt][nt], 0, 0, 0);
                acc[mt][nt] = __builtin_amdgcn_mfma_f32_16x16x32_bf16(al, bfr[nt], acc[mt][nt], 0, 0, 0);
            }
        }
    };

    const int NT = K >> 5;
    STAGE(0, 0);
    STAGE(1, 32);
    VMCNT(6);  // tile 0 landed (6 newer in flight)
    BAR();
    for (int i = 0; i < NT - 2; ++i) {
        const int buf = i & 1;
        mfma_step(buf);
        BAR();                        // all waves done reading buf
        STAGE(buf, (i + 2) * 32);     // refill buf with tile i+2
        VMCNT(6);                     // tile i+1 landed
        BAR();
    }
    mfma_step((NT - 2) & 1);
    BAR();
    VMCNT(0);                         // last tile landed
    BAR();
    mfma_step((NT - 1) & 1);
#undef STAGE

#pragma unroll
    for (int nt = 0; nt < 4; ++nt) {
        int gcol = bn * 128 + wn * 64 + nt * 16 + rl;
        float bv = 0.f;
        if (bias0) bv += bias0[gcol];
        if (bias1) bv += bias1[gcol];
        int outcol = gcol;
        if (permute) {
            int g = gcol >> 10, cell = gcol & 1023;
            outcol = (cell >> 3) * 32 + g * 8 + (cell & 7);
        }
#pragma unroll
        for (int mt = 0; mt < 4; ++mt) {
#pragma unroll
            for (int j = 0; j < 4; ++j) {
                int grow = bm * 128 + wm * 64 + mt * 16 + kg * 4 + j;
                if (grow < Mr) {
                    float v = acc[mt][nt][j] + bv;
                    float* p = &C[(size_t)grow * ldc + outcol];
                    if (ntc) __builtin_nontemporal_store(v, p);
                    else *p = v;
                }
            }
        }
    }
}

// Per-step fused kernel: gates (128 x 32 slice) = h_prev @ Whh_slice^T + ig_t,
// then LSTM cell update. Grid = 128 blocks x 512 threads (8 waves).
// Block bn owns cells [bn*8, bn*8+8) = 32 gate cols n=g*8+ci.
// BK=128 (8 K-iterations), double-buffered, counted-vmcnt pipeline.
// ig2 is the permuted ig: ig2[row][bn*32 + g*8 + ci].
__global__ __launch_bounds__(512) void step_kernel(
    const bf16* __restrict__ hhi_prev, const bf16* __restrict__ hlo_prev,
    const bf16* __restrict__ Whh, const float* __restrict__ ig2,
    const int* __restrict__ meta, float* __restrict__ cst,
    bf16* __restrict__ hhi_out, bf16* __restrict__ hlo_out, int t) {
    const int bn = blockIdx.x;
    const int tid = threadIdx.x;
    const int wave = tid >> 6, lane = tid & 63;
    const int kg = lane >> 4, rl = lane & 15;
    const int wr = wave & 3, wc = wave >> 2;

    __shared__ bf16 sAh[2][16][128][8];  // 64 KB dbuf, BK=128
    __shared__ bf16 sAl[2][16][128][8];  // 64 KB dbuf
    __shared__ bf16 sW[2][16][32][8];    // 16 KB dbuf
    __shared__ float Gs[64][33];         // 8.4 KB (two-pass)

    const int col = wc * 16 + rl;
    const int r0 = wr * 32 + kg * 4;
    const int bsz_t = meta[4 + t];

    // hoisted loads (consumed after the K-loop -> hidden under it)
    const float* igt = ig2 + (size_t)t * BDIM * NG + bn * 32;
    float igv0[4], igv1[4];
#pragma unroll
    for (int j = 0; j < 4; ++j) igv0[j] = igt[(size_t)(r0 + j) * NG + col];
#pragma unroll
    for (int j = 0; j < 4; ++j) igv1[j] = igt[(size_t)(r0 + 16 + j) * NG + col];

    float c_old[2], h_prev[2];
#pragma unroll
    for (int q = 0; q < 2; ++q) {
        int p = tid + q * 512;
        size_t o = (size_t)(p >> 3) * HDIM + bn * 8 + (p & 7);
        if (t == 0) { c_old[q] = 0.f; h_prev[q] = 0.f; }
        else {
            c_old[q] = cst[o];
            h_prev[q] = (float)hhi_prev[o] + (float)hlo_prev[o];
        }
    }

    f32x4 acc0 = {}, acc1 = {};
    if (t > 0) {
        const int sr = tid & 127;  // staging row
        const int sk = tid >> 7;   // 0..3: k-octets {sk, sk+4, sk+8, sk+12}
        const bf16* pAh = hhi_prev + (size_t)sr * HDIM + sk * 8;
        const bf16* pAl = hlo_prev + (size_t)sr * HDIM + sk * 8;
        // W granule: k8 = tid>>5 (0..15), n = tid&31 -> LDS addr = tid*16 (linear)
        const int wn_ = tid & 31;
        const int wk8 = tid >> 5;
        const int grow = (wn_ >> 3) * HDIM + bn * 8 + (wn_ & 7);
        const bf16* pW = Whh + (size_t)grow * HDIM + wk8 * 8;

#define STAGE_H(BUF, KT)                                       \
    {                                                          \
        gload16(pAh + (KT), &sAh[BUF][sk][sr][0]);             \
        gload16(pAh + (KT) + 32, &sAh[BUF][sk + 4][sr][0]);    \
        gload16(pAh + (KT) + 64, &sAh[BUF][sk + 8][sr][0]);    \
        gload16(pAh + (KT) + 96, &sAh[BUF][sk + 12][sr][0]);   \
        gload16(pAl + (KT), &sAl[BUF][sk][sr][0]);             \
        gload16(pAl + (KT) + 32, &sAl[BUF][sk + 4][sr][0]);    \
        gload16(pAl + (KT) + 64, &sAl[BUF][sk + 8][sr][0]);    \
        gload16(pAl + (KT) + 96, &sAl[BUF][sk + 12][sr][0]);   \
        gload16(pW + (KT), &sW[BUF][wk8][wn_][0]);             \
    }

        auto mfma_body = [&](int buf) {
#pragma unroll
            for (int ks = 0; ks < 4; ++ks) {
                bf16x8 bw = *(const bf16x8*)&sW[buf][ks * 4 + kg][col][0];
                bf16x8 ah0 = *(const bf16x8*)&sAh[buf][ks * 4 + kg][wr * 32 + rl][0];
                bf16x8 al0 = *(const bf16x8*)&sAl[buf][ks * 4 + kg][wr * 32 + rl][0];
                acc0 = __builtin_amdgcn_mfma_f32_16x16x32_bf16(ah0, bw, acc0, 0, 0, 0);
                acc0 = __builtin_amdgcn_mfma_f32_16x16x32_bf16(al0, bw, acc0, 0, 0, 0);
                bf16x8 ah1 = *(const bf16x8*)&sAh[buf][ks * 4 + kg][wr * 32 + 16 + rl][0];
                bf16x8 al1 = *(const bf16x8*)&sAl[buf][ks * 4 + kg][wr * 32 + 16 + rl][0];
                acc1 = __builtin_amdgcn_mfma_f32_16x16x32_bf16(ah1, bw, acc1, 0, 0, 0);
                acc1 = __builtin_amdgcn_mfma_f32_16x16x32_bf16(al1, bw, acc1, 0, 0, 0);
            }
        };

        STAGE_H(0, 0);
        STAGE_H(1, 128);
        VMCNT(9);  // tile 0 landed (9 newer in flight)
        BAR();
#pragma unroll
        for (int i = 0; i < 6; ++i) {
            const int buf = i & 1;
            mfma_body(buf);
            BAR();                          // all waves done reading buf
            STAGE_H(buf, (i + 2) * 128);    // refill buf with tile i+2
            VMCNT(9);                       // tile i+1 landed
            BAR();
        }
        mfma_body(0);
        BAR();
        VMCNT(0);                           // last tile landed
        BAR();
        mfma_body(1);
#undef STAGE_H
    }

    // Two passes over batch halves: waves wr<2 own rows 0..63, wr>=2 rows 64..127.
#pragma unroll
    for (int pass = 0; pass < 2; ++pass) {
        if ((wr >> 1) == pass) {
            int rb = r0 - pass * 64;
#pragma unroll
            for (int j = 0; j < 4; ++j) Gs[rb + j][col] = acc0[j] + igv0[j];
#pragma unroll
            for (int j = 0; j < 4; ++j) Gs[rb + 16 + j][col] = acc1[j] + igv1[j];
        }
        __syncthreads();
        {
            int b = pass * 64 + (tid >> 3);
            int ci = tid & 7;
            float gi_ = Gs[b - pass * 64][ci];
            float gf = Gs[b - pass * 64][8 + ci];
            float gg = Gs[b - pass * 64][16 + ci];
            float go = Gs[b - pass * 64][24 + ci];
            float i_ = 1.f / (1.f + expf(-gi_));
            float f_ = 1.f / (1.f + expf(-gf));
            float g_ = tanhf(gg);
            float o_ = 1.f / (1.f + expf(-go));
            float c_new = f_ * c_old[pass] + i_ * g_;
            float h_new = o_ * tanhf(c_new);
            bool active = b < bsz_t;
            float h_out = active ? h_new : h_prev[pass];
            size_t o = (size_t)b * HDIM + bn * 8 + ci;
            if (active) cst[o] = c_new;
            bf16 hi = (bf16)h_out;
            hhi_out[o] = hi;
            hlo_out[o] = (bf16)(h_out - (float)hi);
        }
        __syncthreads();
    }
}

__global__ void hc_out_kernel(const bf16* __restrict__ h0hi, const bf16* __restrict__ h0lo,
                              const bf16* __restrict__ h1hi, const bf16* __restrict__ h1lo,
                              const float* __restrict__ c0, const float* __restrict__ c1,
                              const int* __restrict__ meta, float* __restrict__ out) {
    const int total = meta[1];
    const int bs_last = meta[2];
    size_t base = (size_t)total * VDIM;
    int idx = blockIdx.x * 256 + threadIdx.x;  // 2*B*H
    int l = idx >> 17;
    int b = (idx >> 10) & 127;
    int j = idx & 1023;
    if (b >= bs_last) return;
    const bf16* hh = l ? h1hi : h0hi;
    const bf16* hl = l ? h1lo : h0lo;
    const float* cx = l ? c1 : c0;
    size_t o = (size_t)b * HDIM + j;
    size_t last = (size_t)(SDIM - 1) * BDIM * HDIM;
    float hv = (float)hh[last + o] + (float)hl[last + o];
    out[base + ((size_t)l * bs_last + b) * HDIM + j] = hv;
    out[base + (size_t)2 * bs_last * HDIM + ((size_t)l * bs_last + b) * HDIM + j] = cx[o];
}

extern "C" void kernel_launch(void* const* d_in, const int* in_sizes, int n_in,
                              void* d_out, int out_size, void* d_ws, size_t ws_size,
                              hipStream_t stream) {
    const float* features = (const float*)d_in[0];
    const int* src_tokens = (const int*)d_in[1];
    const int* lengths = (const int*)d_in[2];
    const float* embedW = (const float*)d_in[3];
    const float* w_ih0 = (const float*)d_in[4];
    const float* w_hh0 = (const float*)d_in[5];
    const float* b_ih0 = (const float*)d_in[6];
    const float* b_hh0 = (const float*)d_in[7];
    const float* w_ih1 = (const float*)d_in[8];
    const float* w_hh1 = (const float*)d_in[9];
    const float* b_ih1 = (const float*)d_in[10];
    const float* b_hh1 = (const float*)d_in[11];
    const float* linW = (const float*)d_in[12];
    const float* linb = (const float*)d_in[13];
    float* out = (float*)d_out;

    char* ws = (char*)d_ws;
    size_t off = 0;
    auto alloc = [&](size_t bytes) -> char* {
        char* p = ws + off;
        off = (off + bytes + 255) & ~(size_t)255;
        return p;
    };
    int* meta = (int*)alloc(META_INTS * 4);
    bf16* wih0b = (bf16*)alloc((size_t)NG * EDIM * 2);
    bf16* whh0b = (bf16*)alloc((size_t)NG * HDIM * 2);
    bf16* wih1b = (bf16*)alloc((size_t)NG * HDIM * 2);
    bf16* whh1b = (bf16*)alloc((size_t)NG * HDIM * 2);
    bf16* linWb = (bf16*)alloc((size_t)VDIM * HDIM * 2);
    bf16* x0hi = (bf16*)alloc((size_t)SDIM * BDIM * EDIM * 2);
    bf16* x0lo = (bf16*)alloc((size_t)SDIM * BDIM * EDIM * 2);
    bf16* hs0hi = (bf16*)alloc((size_t)SDIM * BDIM * HDIM * 2);
    bf16* hs0lo = (bf16*)alloc((size_t)SDIM * BDIM * HDIM * 2);
    bf16* hs1hi = (bf16*)alloc((size_t)SDIM * BDIM * HDIM * 2);
    bf16* hs1lo = (bf16*)alloc((size_t)SDIM * BDIM * HDIM * 2);
    float* c0 = (float*)alloc((size_t)BDIM * HDIM * 4);
    float* c1 = (float*)alloc((size_t)BDIM * HDIM * 4);
    float* ig = (float*)alloc((size_t)SDIM * BDIM * NG * 4);

    meta_kernel<<<1, 64, 0, stream>>>(lengths, meta);

    cvt_bf16_kernel<<<(NG * EDIM / 8 + 255) / 256, 256, 0, stream>>>(w_ih0, wih0b, NG * EDIM / 8);
    cvt_bf16_kernel<<<(NG * HDIM / 8 + 255) / 256, 256, 0, stream>>>(w_hh0, whh0b, NG * HDIM / 8);
    cvt_bf16_kernel<<<(NG * HDIM / 8 + 255) / 256, 256, 0, stream>>>(w_ih1, wih1b, NG * HDIM / 8);
    cvt_bf16_kernel<<<(NG * HDIM / 8 + 255) / 256, 256, 0, stream>>>(w_hh1, whh1b, NG * HDIM / 8);
    cvt_bf16_kernel<<<(VDIM * HDIM / 8 + 255) / 256, 256, 0, stream>>>(linW, linWb, VDIM * HDIM / 8);

    gather_x0_kernel<<<(SDIM * BDIM * EDIM / 8) / 256, 256, 0, stream>>>(
        features, src_tokens, embedW, x0hi, x0lo);

    // ig0 = x0 @ w_ih0^T + b_ih0 + b_hh0 (permuted cols)
    gemm_bulk<<<dim3(SDIM * BDIM / 128, NG / 128), 256, 0, stream>>>(
        x0hi, x0lo, wih0b, ig, b_ih0, b_hh0, nullptr, nullptr, SDIM * BDIM, EDIM, NG, 1, 0);

    const size_t BH = (size_t)BDIM * HDIM;

    // ---- layer 0: per-step launches ----
    for (int t = 0; t < SDIM; ++t) {
        const bf16* hh = hs0hi + (size_t)(t > 0 ? t - 1 : 0) * BH;
        const bf16* hl = hs0lo + (size_t)(t > 0 ? t - 1 : 0) * BH;
        step_kernel<<<128, 512, 0, stream>>>(
            hh, hl, whh0b, ig, meta, c0,
            hs0hi + (size_t)t * BH, hs0lo + (size_t)t * BH, t);
    }

    // ig1 = hs0 @ w_ih1^T + b_ih1 + b_hh1 (permuted cols)
    gemm_bulk<<<dim3(SDIM * BDIM / 128, NG / 128), 256, 0, stream>>>(
        hs0hi, hs0lo, wih1b, ig, b_ih1, b_hh1, nullptr, nullptr, SDIM * BDIM, HDIM, NG, 1, 0);

    // ---- layer 1 ----
    for (int t = 0; t < SDIM; ++t) {
        const bf16* hh = hs1hi + (size_t)(t > 0 ? t - 1 : 0) * BH;
        const bf16* hl = hs1lo + (size_t)(t > 0 ? t - 1 : 0) * BH;
        step_kernel<<<128, 512, 0, stream>>>(
            hh, hl, whh1b, ig, meta, c1,
            hs1hi + (size_t)t * BH, hs1lo + (size_t)t * BH, t);
    }

    // out[r,:] = hs1[src_row[r],:] @ linW^T + linb (non-temporal C stores)
    gemm_bulk<<<dim3(SDIM * BDIM / 128, VDIM / 128), 256, 0, stream>>>(
        hs1hi, hs1lo, linWb, out, linb, nullptr, meta + 132, meta + 1, SDIM * BDIM, HDIM, VDIM, 0, 1);

    hc_out_kernel<<<(2 * BDIM * HDIM) / 256, 256, 0, stream>>>(
        hs0hi, hs0lo, hs1hi, hs1lo, c0, c1, meta, out);
}

// Round 9
// 3400.944 us; speedup vs baseline: 1.4699x; 1.4699x over previous
//
#include <hip/hip_runtime.h>
#include <math.h>

#define EDIM 512
#define HDIM 1024
#define VDIM 32000
#define BDIM 128
#define SDIM 64
#define NG 4096

typedef __bf16 bf16;
typedef bf16 bf16x8 __attribute__((ext_vector_type(8)));
typedef float f32x4 __attribute__((ext_vector_type(4)));

__device__ __forceinline__ void gload16(const bf16* g, bf16* l) {
    __builtin_amdgcn_global_load_lds(
        (const __attribute__((address_space(1))) void*)g,
        (__attribute__((address_space(3))) void*)l, 16, 0, 0);
}

#define VMCNT(N)                                              \
    {                                                         \
        asm volatile("s_waitcnt vmcnt(" #N ")" ::: "memory"); \
        __builtin_amdgcn_sched_barrier(0);                    \
    }
#define BAR() __builtin_amdgcn_s_barrier()

// meta: [0]=T,[1]=total,[2]=bs_last,[3]=pad,[4..67]=bsz,[68..131]=off,
// [132..132+8192)=src_row
#define META_INTS (132 + BDIM * SDIM)

__global__ void meta_kernel(const int* __restrict__ lengths, int* __restrict__ meta) {
    __shared__ int s_bsz[SDIM];
    __shared__ int s_off[SDIM];
    int t = threadIdx.x;
    int cnt = 0;
    for (int b = 0; b < BDIM; ++b) cnt += (lengths[b] > t) ? 1 : 0;
    s_bsz[t] = cnt;
    __syncthreads();
    if (t == 0) {
        int acc = 0;
        for (int i = 0; i < SDIM; ++i) { s_off[i] = acc; acc += s_bsz[i]; }
        int T = lengths[0];
        meta[0] = T;
        meta[1] = acc;
        meta[2] = s_bsz[T - 1];
        meta[3] = 0;
    }
    __syncthreads();
    meta[4 + t] = s_bsz[t];
    meta[68 + t] = s_off[t];
    for (int b = 0; b < s_bsz[t]; ++b) meta[132 + s_off[t] + b] = t * BDIM + b;
}

__global__ void cvt_bf16_kernel(const float* __restrict__ src, bf16* __restrict__ dst, int n8) {
    int idx = blockIdx.x * 256 + threadIdx.x;
    if (idx >= n8) return;
    float4 a = ((const float4*)src)[(size_t)idx * 2];
    float4 b = ((const float4*)src)[(size_t)idx * 2 + 1];
    float v[8] = {a.x, a.y, a.z, a.w, b.x, b.y, b.z, b.w};
    bf16x8 o;
#pragma unroll
    for (int i = 0; i < 8; ++i) o[i] = (bf16)v[i];
    *(bf16x8*)(dst + (size_t)idx * 8) = o;
}

__global__ void gather_x0_kernel(const float* __restrict__ features,
                                 const int* __restrict__ tokens,
                                 const float* __restrict__ embedW,
                                 bf16* __restrict__ xhi, bf16* __restrict__ xlo) {
    int idx = blockIdx.x * 256 + threadIdx.x;
    int r = idx >> 6;
    int c = (idx & 63) * 8;
    int t = r >> 7, b = r & 127;
    const float* src = (t == 0) ? (features + (size_t)b * EDIM)
                                : (embedW + (size_t)tokens[b * SDIM + (t - 1)] * EDIM);
    float4 a = *(const float4*)(src + c);
    float4 d = *(const float4*)(src + c + 4);
    float v[8] = {a.x, a.y, a.z, a.w, d.x, d.y, d.z, d.w};
    bf16x8 hi, lo;
#pragma unroll
    for (int i = 0; i < 8; ++i) {
        hi[i] = (bf16)v[i];
        lo[i] = (bf16)(v[i] - (float)hi[i]);
    }
    size_t o = (size_t)r * EDIM + c;
    *(bf16x8*)(xhi + o) = hi;
    *(bf16x8*)(xlo + o) = lo;
}

// C[M x N] = (Ahi + Alo) @ B^T + bias0 + bias1.  Natural column layout.
// Tile 128x128, BK=32, 256 threads. blockIdx.x = bn (fastest: A tile L2-hot),
// blockIdx.y = bm. Epilogue: LDS-transposed, float4 full-line stores (no RMW).
__global__ __launch_bounds__(256) void gemm_bulk(
    const bf16* __restrict__ Ahi, const bf16* __restrict__ Alo,
    const bf16* __restrict__ Bb, float* __restrict__ C,
    const float* __restrict__ bias0, const float* __restrict__ bias1,
    const int* __restrict__ srcrow, const int* __restrict__ mdyn,
    int M, int K, int ldc) {
    const int Mr = mdyn ? mdyn[0] : M;
    const int bn = blockIdx.x;
    const int bm = blockIdx.y;
    if (bm * 128 >= Mr) return;

    const int tid = threadIdx.x;
    const int wave = tid >> 6, lane = tid & 63;
    const int kg = lane >> 4, rl = lane & 15;
    const int wm = wave >> 1, wn = wave & 1;

    __shared__ char smem[49152];
    bf16* sAh_ = (bf16*)smem;             // [2][4][128][8] = 16 KB
    bf16* sAl_ = (bf16*)(smem + 16384);   // 16 KB
    bf16* sBB_ = (bf16*)(smem + 32768);   // 16 KB
    float(*sC)[132] = (float(*)[132])smem;  // 64x132x4 = 33.8 KB (aliased)

#define AHI(buf, k8, row) (sAh_ + ((((buf)*4 + (k8)) * 128 + (row)) * 8))
#define ALO(buf, k8, row) (sAl_ + ((((buf)*4 + (k8)) * 128 + (row)) * 8))
#define SBB(buf, k8, row) (sBB_ + ((((buf)*4 + (k8)) * 128 + (row)) * 8))

    const int sr = tid & 127;
    const int skg = tid >> 7;
    int arow_g = bm * 128 + sr;
    int arow = (arow_g < Mr) ? (srcrow ? srcrow[arow_g] : arow_g) : (srcrow ? srcrow[0] : 0);
    const bf16* pAhi = Ahi + (size_t)arow * K + skg * 8;
    const bf16* pAlo = Alo + (size_t)arow * K + skg * 8;
    const bf16* pB = Bb + ((size_t)bn * 128 + sr) * K + skg * 8;

    f32x4 acc[4][4] = {};

#define STAGE(BUF, KT)                                  \
    {                                                   \
        gload16(pAhi + (KT), AHI(BUF, skg, sr));        \
        gload16(pAhi + (KT) + 16, AHI(BUF, skg + 2, sr));\
        gload16(pAlo + (KT), ALO(BUF, skg, sr));        \
        gload16(pAlo + (KT) + 16, ALO(BUF, skg + 2, sr));\
        gload16(pB + (KT), SBB(BUF, skg, sr));          \
        gload16(pB + (KT) + 16, SBB(BUF, skg + 2, sr)); \
    }

    auto mfma_step = [&](int buf) {
        bf16x8 bfr[4];
#pragma unroll
        for (int nt = 0; nt < 4; ++nt)
            bfr[nt] = *(const bf16x8*)SBB(buf, kg, wn * 64 + nt * 16 + rl);
#pragma unroll
        for (int mt = 0; mt < 4; ++mt) {
            bf16x8 ah = *(const bf16x8*)AHI(buf, kg, wm * 64 + mt * 16 + rl);
            bf16x8 al = *(const bf16x8*)ALO(buf, kg, wm * 64 + mt * 16 + rl);
#pragma unroll
            for (int nt = 0; nt < 4; ++nt) {
                acc[mt][nt] = __builtin_amdgcn_mfma_f32_16x16x32_bf16(ah, bfr[nt], acc[mt][nt], 0, 0, 0);
                acc[mt][nt] = __builtin_amdgcn_mfma_f32_16x16x32_bf16(al, bfr[nt], acc[mt][nt], 0, 0, 0);
            }
        }
    };

    const int NT = K >> 5;
    STAGE(0, 0);
    STAGE(1, 32);
    VMCNT(6);
    BAR();
    for (int i = 0; i < NT - 2; ++i) {
        const int buf = i & 1;
        mfma_step(buf);
        BAR();
        STAGE(buf, (i + 2) * 32);
        VMCNT(6);
        BAR();
    }
    mfma_step((NT - 2) & 1);
    BAR();
    VMCNT(0);
    BAR();
    mfma_step((NT - 1) & 1);
#undef STAGE

    // bias per output col (nt)
    float bvv[4];
#pragma unroll
    for (int nt = 0; nt < 4; ++nt) {
        int gcol = bn * 128 + wn * 64 + nt * 16 + rl;
        float bv = 0.f;
        if (bias0) bv += bias0[gcol];
        if (bias1) bv += bias1[gcol];
        bvv[nt] = bv;
    }

    __syncthreads();  // all staging reads done before sC aliases the buffers
#pragma unroll
    for (int pass = 0; pass < 2; ++pass) {
        if (wm == pass) {
#pragma unroll
            for (int mt = 0; mt < 4; ++mt)
#pragma unroll
                for (int nt = 0; nt < 4; ++nt)
#pragma unroll
                    for (int j = 0; j < 4; ++j)
                        sC[mt * 16 + kg * 4 + j][wn * 64 + nt * 16 + rl] =
                            acc[mt][nt][j] + bvv[nt];
        }
        __syncthreads();
        int grow0 = bm * 128 + pass * 64;
#pragma unroll
        for (int q = 0; q < 8; ++q) {
            int gi = q * 256 + tid;
            int row = gi >> 5, c4 = (gi & 31) * 4;
            int grow = grow0 + row;
            if (grow < Mr) {
                float4 v = *(const float4*)&sC[row][c4];
                *(float4*)&C[(size_t)grow * ldc + bn * 128 + c4] = v;
            }
        }
        __syncthreads();
    }
}

// Per-step fused kernel: grid dim3(128 cell-groups, 2 batch-halves), 512 thr.
// Block (bn,bh): gates tile 64(batch) x 32(gate cols for cells bn*8..+8),
// = h_prev[bh half] @ Whh_slice^T + ig_t, then cell update. ig natural layout.
__global__ __launch_bounds__(512) void step_kernel(
    const bf16* __restrict__ hhi_prev, const bf16* __restrict__ hlo_prev,
    const bf16* __restrict__ Whh, const float* __restrict__ ig,
    const int* __restrict__ meta, float* __restrict__ cst,
    bf16* __restrict__ hhi_out, bf16* __restrict__ hlo_out, int t) {
    const int bn = blockIdx.x;
    const int bh = blockIdx.y;
    const int tid = threadIdx.x;
    const int wave = tid >> 6, lane = tid & 63;
    const int kg = lane >> 4, rl = lane & 15;
    const int wr = wave & 3, wc = wave >> 2;

    __shared__ bf16 sAh[2][16][64][8];  // 32 KB dbuf, BK=128
    __shared__ bf16 sAl[2][16][64][8];  // 32 KB
    __shared__ bf16 sW[2][16][32][8];   // 16 KB
    __shared__ float Gs[64][33];        // 8.4 KB

    const int row0 = bh * 64;
    const int col = wc * 16 + rl;   // 0..31 gate col
    const int r0 = wr * 16 + kg * 4;  // local row base
    const int bsz_t = meta[4 + t];
    const float* igt = ig + (size_t)t * BDIM * NG;

    // hoisted ig (natural layout: [row][g*1024 + cell])
    const int g = col >> 3, cic = col & 7;
    float igv[4];
#pragma unroll
    for (int j = 0; j < 4; ++j)
        igv[j] = igt[(size_t)(row0 + r0 + j) * NG + g * 1024 + bn * 8 + cic];

    // hoisted c/h_prev (1 per thread)
    const int bloc = tid >> 3, cci = tid & 7;
    const int bglob = row0 + bloc;
    const size_t oglob = (size_t)bglob * HDIM + bn * 8 + cci;
    float c_old, h_prev;
    if (t == 0) { c_old = 0.f; h_prev = 0.f; }
    else {
        c_old = cst[oglob];
        h_prev = (float)hhi_prev[oglob] + (float)hlo_prev[oglob];
    }

    f32x4 acc = {};
    if (t > 0) {
        const int srow = tid & 63;
        const int sk8 = tid >> 6;  // 0..7
        const bf16* pAh0 = hhi_prev + (size_t)(row0 + srow) * HDIM + sk8 * 8;
        const bf16* pAl0 = hlo_prev + (size_t)(row0 + srow) * HDIM + sk8 * 8;
        const int wrow = tid & 31, wk8 = tid >> 5;  // 0..15
        const bf16* pW = Whh + (size_t)((wrow >> 3) * HDIM + bn * 8 + (wrow & 7)) * HDIM + wk8 * 8;

#define STAGE_H(BUF, KT)                                     \
    {                                                        \
        gload16(pAh0 + (KT), &sAh[BUF][sk8][srow][0]);       \
        gload16(pAh0 + (KT) + 64, &sAh[BUF][8 + sk8][srow][0]);\
        gload16(pAl0 + (KT), &sAl[BUF][sk8][srow][0]);       \
        gload16(pAl0 + (KT) + 64, &sAl[BUF][8 + sk8][srow][0]);\
        gload16(pW + (KT), &sW[BUF][wk8][wrow][0]);          \
    }

        auto mfma_body = [&](int buf) {
#pragma unroll
            for (int ks = 0; ks < 4; ++ks) {
                bf16x8 bw = *(const bf16x8*)&sW[buf][ks * 4 + kg][col][0];
                bf16x8 ah = *(const bf16x8*)&sAh[buf][ks * 4 + kg][wr * 16 + rl][0];
                bf16x8 al = *(const bf16x8*)&sAl[buf][ks * 4 + kg][wr * 16 + rl][0];
                acc = __builtin_amdgcn_mfma_f32_16x16x32_bf16(ah, bw, acc, 0, 0, 0);
                acc = __builtin_amdgcn_mfma_f32_16x16x32_bf16(al, bw, acc, 0, 0, 0);
            }
        };

        STAGE_H(0, 0);
        STAGE_H(1, 128);
        VMCNT(5);
        BAR();
#pragma unroll
        for (int i = 0; i < 6; ++i) {
            const int buf = i & 1;
            mfma_body(buf);
            BAR();
            STAGE_H(buf, (i + 2) * 128);
            VMCNT(5);
            BAR();
        }
        mfma_body(0);
        BAR();
        VMCNT(0);
        BAR();
        mfma_body(1);
#undef STAGE_H
    }

    // gates -> Gs (D: row = r0 + j, col)
#pragma unroll
    for (int j = 0; j < 4; ++j) Gs[r0 + j][col] = acc[j] + igv[j];
    __syncthreads();

    {
        float gi_ = Gs[bloc][cic];
        float gf = Gs[bloc][8 + cic];
        float gg = Gs[bloc][16 + cic];
        float go = Gs[bloc][24 + cic];
        float i_ = 1.f / (1.f + expf(-gi_));
        float f_ = 1.f / (1.f + expf(-gf));
        float g_ = tanhf(gg);
        float o_ = 1.f / (1.f + expf(-go));
        float c_new = f_ * c_old + i_ * g_;
        float h_new = o_ * tanhf(c_new);
        bool active = bglob < bsz_t;
        float h_out = active ? h_new : h_prev;
        if (active) cst[oglob] = c_new;
        bf16 hi = (bf16)h_out;
        hhi_out[oglob] = hi;
        hlo_out[oglob] = (bf16)(h_out - (float)hi);
    }
}

__global__ void hc_out_kernel(const bf16* __restrict__ h0hi, const bf16* __restrict__ h0lo,
                              const bf16* __restrict__ h1hi, const bf16* __restrict__ h1lo,
                              const float* __restrict__ c0, const float* __restrict__ c1,
                              const int* __restrict__ meta, float* __restrict__ out) {
    const int total = meta[1];
    const int bs_last = meta[2];
    size_t base = (size_t)total * VDIM;
    int idx = blockIdx.x * 256 + threadIdx.x;
    int l = idx >> 17;
    int b = (idx >> 10) & 127;
    int j = idx & 1023;
    if (b >= bs_last) return;
    const bf16* hh = l ? h1hi : h0hi;
    const bf16* hl = l ? h1lo : h0lo;
    const float* cx = l ? c1 : c0;
    size_t o = (size_t)b * HDIM + j;
    size_t last = (size_t)(SDIM - 1) * BDIM * HDIM;
    float hv = (float)hh[last + o] + (float)hl[last + o];
    out[base + ((size_t)l * bs_last + b) * HDIM + j] = hv;
    out[base + (size_t)2 * bs_last * HDIM + ((size_t)l * bs_last + b) * HDIM + j] = cx[o];
}

extern "C" void kernel_launch(void* const* d_in, const int* in_sizes, int n_in,
                              void* d_out, int out_size, void* d_ws, size_t ws_size,
                              hipStream_t stream) {
    const float* features = (const float*)d_in[0];
    const int* src_tokens = (const int*)d_in[1];
    const int* lengths = (const int*)d_in[2];
    const float* embedW = (const float*)d_in[3];
    const float* w_ih0 = (const float*)d_in[4];
    const float* w_hh0 = (const float*)d_in[5];
    const float* b_ih0 = (const float*)d_in[6];
    const float* b_hh0 = (const float*)d_in[7];
    const float* w_ih1 = (const float*)d_in[8];
    const float* w_hh1 = (const float*)d_in[9];
    const float* b_ih1 = (const float*)d_in[10];
    const float* b_hh1 = (const float*)d_in[11];
    const float* linW = (const float*)d_in[12];
    const float* linb = (const float*)d_in[13];
    float* out = (float*)d_out;

    char* ws = (char*)d_ws;
    size_t off = 0;
    auto alloc = [&](size_t bytes) -> char* {
        char* p = ws + off;
        off = (off + bytes + 255) & ~(size_t)255;
        return p;
    };
    int* meta = (int*)alloc(META_INTS * 4);
    bf16* wih0b = (bf16*)alloc((size_t)NG * EDIM * 2);
    bf16* whh0b = (bf16*)alloc((size_t)NG * HDIM * 2);
    bf16* wih1b = (bf16*)alloc((size_t)NG * HDIM * 2);
    bf16* whh1b = (bf16*)alloc((size_t)NG * HDIM * 2);
    bf16* linWb = (bf16*)alloc((size_t)VDIM * HDIM * 2);
    bf16* x0hi = (bf16*)alloc((size_t)SDIM * BDIM * EDIM * 2);
    bf16* x0lo = (bf16*)alloc((size_t)SDIM * BDIM * EDIM * 2);
    bf16* hs0hi = (bf16*)alloc((size_t)SDIM * BDIM * HDIM * 2);
    bf16* hs0lo = (bf16*)alloc((size_t)SDIM * BDIM * HDIM * 2);
    bf16* hs1hi = (bf16*)alloc((size_t)SDIM * BDIM * HDIM * 2);
    bf16* hs1lo = (bf16*)alloc((size_t)SDIM * BDIM * HDIM * 2);
    float* c0 = (float*)alloc((size_t)BDIM * HDIM * 4);
    float* c1 = (float*)alloc((size_t)BDIM * HDIM * 4);
    float* ig = (float*)alloc((size_t)SDIM * BDIM * NG * 4);

    meta_kernel<<<1, 64, 0, stream>>>(lengths, meta);

    cvt_bf16_kernel<<<(NG * EDIM / 8 + 255) / 256, 256, 0, stream>>>(w_ih0, wih0b, NG * EDIM / 8);
    cvt_bf16_kernel<<<(NG * HDIM / 8 + 255) / 256, 256, 0, stream>>>(w_hh0, whh0b, NG * HDIM / 8);
    cvt_bf16_kernel<<<(NG * HDIM / 8 + 255) / 256, 256, 0, stream>>>(w_ih1, wih1b, NG * HDIM / 8);
    cvt_bf16_kernel<<<(NG * HDIM / 8 + 255) / 256, 256, 0, stream>>>(w_hh1, whh1b, NG * HDIM / 8);
    cvt_bf16_kernel<<<(VDIM * HDIM / 8 + 255) / 256, 256, 0, stream>>>(linW, linWb, VDIM * HDIM / 8);

    gather_x0_kernel<<<(SDIM * BDIM * EDIM / 8) / 256, 256, 0, stream>>>(
        features, src_tokens, embedW, x0hi, x0lo);

    // ig0 = x0 @ w_ih0^T + b_ih0 + b_hh0  (natural layout, bn-fastest grid)
    gemm_bulk<<<dim3(NG / 128, SDIM * BDIM / 128), 256, 0, stream>>>(
        x0hi, x0lo, wih0b, ig, b_ih0, b_hh0, nullptr, nullptr, SDIM * BDIM, EDIM, NG);

    const size_t BH = (size_t)BDIM * HDIM;

    for (int t = 0; t < SDIM; ++t) {
        const bf16* hh = hs0hi + (size_t)(t > 0 ? t - 1 : 0) * BH;
        const bf16* hl = hs0lo + (size_t)(t > 0 ? t - 1 : 0) * BH;
        step_kernel<<<dim3(128, 2), 512, 0, stream>>>(
            hh, hl, whh0b, ig, meta, c0,
            hs0hi + (size_t)t * BH, hs0lo + (size_t)t * BH, t);
    }

    // ig1 = hs0 @ w_ih1^T + b_ih1 + b_hh1
    gemm_bulk<<<dim3(NG / 128, SDIM * BDIM / 128), 256, 0, stream>>>(
        hs0hi, hs0lo, wih1b, ig, b_ih1, b_hh1, nullptr, nullptr, SDIM * BDIM, HDIM, NG);

    for (int t = 0; t < SDIM; ++t) {
        const bf16* hh = hs1hi + (size_t)(t > 0 ? t - 1 : 0) * BH;
        const bf16* hl = hs1lo + (size_t)(t > 0 ? t - 1 : 0) * BH;
        step_kernel<<<dim3(128, 2), 512, 0, stream>>>(
            hh, hl, whh1b, ig, meta, c1,
            hs1hi + (size_t)t * BH, hs1lo + (size_t)t * BH, t);
    }

    // out[r,:] = hs1[src_row[r],:] @ linW^T + linb
    gemm_bulk<<<dim3(VDIM / 128, SDIM * BDIM / 128), 256, 0, stream>>>(
        hs1hi, hs1lo, linWb, out, linb, nullptr, meta + 132, meta + 1, SDIM * BDIM, HDIM, VDIM);

    hc_out_kernel<<<(2 * BDIM * HDIM) / 256, 256, 0, stream>>>(
        hs0hi, hs0lo, hs1hi, hs1lo, c0, c1, meta, out);
}